// Round 2
// baseline (8157.372 us; speedup 1.0000x reference)
//
#include <hip/hip_runtime.h>
#include <math.h>

#define TLEN 512
#define G4   2048
#define HID  512
#define D2H  1024
#define MLP  256
#define NR   513
#define NWG  32

__device__ __forceinline__ float sigm(float x) { return 1.0f / (1.0f + __expf(-x)); }
__device__ __forceinline__ float tanh_(float x) { return 1.0f - 2.0f / (1.0f + __expf(2.0f * x)); }

// ---------------- pad/copy (zero-pad K dim to multiple of 16) ----------------
__global__ __launch_bounds__(256) void pad_rows(const float* __restrict__ src,
                                                float* __restrict__ dst,
                                                int rows, int ksrc, int kdst) {
    int idx = blockIdx.x * 256 + threadIdx.x;
    if (idx >= rows * kdst) return;
    int r = idx / kdst, k = idx - r * kdst;
    dst[idx] = (k < ksrc) ? src[(long)r * ksrc + k] : 0.0f;
}

// ---------------- tiled fp32 GEMM: Out[dir][m][n] = bias[dir][n] + sum_k X[m][k]*W[dir][n][k]
__global__ __launch_bounds__(256) void gemm_btn(
    const float* __restrict__ X, int ldx,
    const float* __restrict__ W, int ldw, long wsd,
    const float* __restrict__ bias, int bsd,
    float* __restrict__ Out, long osd,
    int M, int N, int K)
{
    int dir = blockIdx.z;
    const float* Wd = W + (long)dir * wsd;
    const float* bd = bias + (long)dir * bsd;
    float* Od = Out + (long)dir * osd;
    int n0 = blockIdx.x * 64, m0 = blockIdx.y * 64;
    __shared__ float As[16][68], Bs[16][68];
    int tid = threadIdx.x;
    int ti = tid >> 4, tj = tid & 15;
    int lr = tid >> 2, lq = tid & 3;
    float acc[4][4] = {};
    for (int k0 = 0; k0 < K; k0 += 16) {
        int mrow = m0 + lr;
        float4 xa = make_float4(0.f, 0.f, 0.f, 0.f);
        if (mrow < M) xa = *(const float4*)(X + (long)mrow * ldx + k0 + lq * 4);
        As[lq * 4 + 0][lr] = xa.x; As[lq * 4 + 1][lr] = xa.y;
        As[lq * 4 + 2][lr] = xa.z; As[lq * 4 + 3][lr] = xa.w;
        float4 wa = *(const float4*)(Wd + (long)(n0 + lr) * ldw + k0 + lq * 4);
        Bs[lq * 4 + 0][lr] = wa.x; Bs[lq * 4 + 1][lr] = wa.y;
        Bs[lq * 4 + 2][lr] = wa.z; Bs[lq * 4 + 3][lr] = wa.w;
        __syncthreads();
#pragma unroll
        for (int kk = 0; kk < 16; ++kk) {
            float4 a = *(const float4*)&As[kk][ti * 4];
            float4 b = *(const float4*)&Bs[kk][tj * 4];
            acc[0][0] += a.x * b.x; acc[0][1] += a.x * b.y; acc[0][2] += a.x * b.z; acc[0][3] += a.x * b.w;
            acc[1][0] += a.y * b.x; acc[1][1] += a.y * b.y; acc[1][2] += a.y * b.z; acc[1][3] += a.y * b.w;
            acc[2][0] += a.z * b.x; acc[2][1] += a.z * b.y; acc[2][2] += a.z * b.z; acc[2][3] += a.z * b.w;
            acc[3][0] += a.w * b.x; acc[3][1] += a.w * b.y; acc[3][2] += a.w * b.z; acc[3][3] += a.w * b.w;
        }
        __syncthreads();
    }
#pragma unroll
    for (int i = 0; i < 4; ++i) {
        int m = m0 + ti * 4 + i;
        if (m < M) {
#pragma unroll
            for (int j = 0; j < 4; ++j) {
                int n = n0 + tj * 4 + j;
                Od[(long)m * N + n] = acc[i][j] + bd[n];
            }
        }
    }
}

// ---------------- persistent per-direction LSTM recurrence ----------------
// grid (NWG, 2): 32 WGs per direction, 256 threads. Each WG owns 16 h-indices
// (64 gate rows); Whh slice lives in registers (128 f32/thread). Per step:
// acquire-poll cnt[dir][s-1], stage h (agent-scope atomic loads) via LDS,
// dot, gates, agent-scope atomic h stores, barrier, release fetch_add.
// 64 WGs <= 256 CUs so all co-resident: spin cannot deadlock.
__global__ __launch_bounds__(256) void lstm_rec(
    const float* __restrict__ Whh,   // [2][2048][512]
    const float* __restrict__ Zpre,  // [2][512][2048] (= Wih@x_t + b)
    float* __restrict__ Y,           // row t: Y + t*1024 + dir*512 + j
    int* __restrict__ cnt)           // [2][512], pre-zeroed
{
    int wg = blockIdx.x;
    int dir = blockIdx.y;
    int tid = threadIdx.x;
    int rl = tid >> 2;          // local row 0..63
    int kp = tid & 3;           // k-part 0..3 (128 each)
    int g = rl >> 4;            // gate 0..3 (i,f,g,o)
    int jj = rl & 15;
    int row_global = g * 512 + wg * 16 + jj;

    const float* wrow = Whh + ((long)dir * G4 + row_global) * HID + kp * 128;
    float4 w4[32];
#pragma unroll
    for (int u = 0; u < 32; ++u) w4[u] = *(const float4*)(wrow + u * 4);

    __shared__ float hs[524];   // h staged, +4 pad per 128-block (bank spread)
    __shared__ float zs[64];
    float c_reg = 0.0f;
    int* mycnt = cnt + dir * TLEN;

    for (int s = 0; s < TLEN; ++s) {
        if (s > 0) {
            if (tid == 0) {
                while (__hip_atomic_load(mycnt + (s - 1), __ATOMIC_ACQUIRE,
                                         __HIP_MEMORY_SCOPE_AGENT) < NWG) {
                    __builtin_amdgcn_s_sleep(1);
                }
            }
            __syncthreads();   // all threads sync-with tid0's acquire
            int rrow = dir ? (TLEN - s) : (s - 1);
            {
                const float* src = Y + (long)rrow * D2H + dir * HID;
                int e = tid * 2;
                float v0 = __hip_atomic_load(src + e,     __ATOMIC_RELAXED, __HIP_MEMORY_SCOPE_AGENT);
                float v1 = __hip_atomic_load(src + e + 1, __ATOMIC_RELAXED, __HIP_MEMORY_SCOPE_AGENT);
                int base = e + (e >> 7) * 4;
                hs[base] = v0; hs[base + 1] = v1;
            }
            __syncthreads();
            const float* hp = &hs[kp * 132];
            float z = 0.0f;
#pragma unroll
            for (int u = 0; u < 32; ++u) {
                float4 hv = *(const float4*)(hp + u * 4);
                z += w4[u].x * hv.x + w4[u].y * hv.y + w4[u].z * hv.z + w4[u].w * hv.w;
            }
            z += __shfl_xor(z, 1);
            z += __shfl_xor(z, 2);
            if (kp == 0) zs[rl] = z;
        } else {
            if (tid < 64) zs[tid] = 0.0f;
        }
        __syncthreads();
        if (tid < 16) {
            int t_x = dir ? (TLEN - 1 - s) : s;
            const float* zp = Zpre + ((long)dir * TLEN + t_x) * G4 + wg * 16 + tid;
            float zi = zs[tid]       + zp[0];
            float zf = zs[16 + tid]  + zp[512];
            float zg = zs[32 + tid]  + zp[1024];
            float zo = zs[48 + tid]  + zp[1536];
            float ig = sigm(zi), fg = sigm(zf), gv = tanh_(zg), og = sigm(zo);
            c_reg = fg * c_reg + ig * gv;
            float h = og * tanh_(c_reg);
            __hip_atomic_store(Y + (long)t_x * D2H + dir * HID + wg * 16 + tid, h,
                               __ATOMIC_RELAXED, __HIP_MEMORY_SCOPE_AGENT);
        }
        __syncthreads();   // all lanes' h stores happen-before tid0's release add
        if (tid == 0) {
            __hip_atomic_fetch_add(mycnt + s, 1, __ATOMIC_RELEASE,
                                   __HIP_MEMORY_SCOPE_AGENT);
        }
    }
}

// ---------------- all-pairs edge scorer ----------------
__global__ __launch_bounds__(256) void pair_score(
    const float* __restrict__ heads, const float* __restrict__ mods,
    const float* __restrict__ w_s, const float* __restrict__ b_s,
    float* __restrict__ out)
{
    __shared__ float hsh[16][260], msh[16][260], wsh[256];
    int tid = threadIdx.x;
    int i0 = blockIdx.y * 16, j0 = blockIdx.x * 16;
    int r = tid >> 4, cq = tid & 15;
#pragma unroll
    for (int u = 0; u < 4; ++u) {
        int col = cq * 16 + u * 4;
        if (col < MLP) {
            float4 hv = make_float4(0.f, 0.f, 0.f, 0.f), mv = hv;
            if (i0 + r < NR) hv = *(const float4*)(heads + (long)(i0 + r) * MLP + col);
            if (j0 + r < NR) mv = *(const float4*)(mods + (long)(j0 + r) * MLP + col);
            *(float4*)&hsh[r][col] = hv;
            *(float4*)&msh[r][col] = mv;
        }
    }
    wsh[tid] = w_s[tid];
    __syncthreads();
    int ti = tid >> 4, tj = tid & 15;
    float acc = 0.0f;
#pragma unroll 4
    for (int h = 0; h < MLP; ++h) {
        acc += wsh[h] * tanh_(hsh[ti][h] + msh[tj][h]);
    }
    int i = i0 + ti, j = j0 + tj;
    if (i < NR && j < NR) out[(long)i * NR + j] = (i == j) ? 0.0f : (acc + b_s[0]);
}

extern "C" void kernel_launch(void* const* d_in, const int* in_sizes, int n_in,
                              void* d_out, int out_size, void* d_ws, size_t ws_size,
                              hipStream_t stream)
{
    const float* x = (const float*)d_in[0];
    float* ws = (float*)d_ws;
    float* Xpad  = ws;                          // 512*512
    float* Wpad  = Xpad + 512 * 512;            // 2*2048*512
    float* Z     = Wpad + 2 * 2048 * 512;       // 2*512*2048
    float* bufA  = Z + 2 * 512 * 2048;          // 512*1024
    float* bufB  = bufA + 512 * 1024;           // 512*1024
    float* Hcat  = bufB + 512 * 1024;           // 513*1024 (row 0 = ROOT zeros)
    float* heads = Hcat + 513 * 1024;           // 513*256
    float* mods  = heads + 513 * 256;           // 513*256
    int*   flags = (int*)(mods + 513 * 256);    // 4*2*512 ints

    hipMemsetAsync(flags, 0, 4 * 2 * TLEN * sizeof(int), stream);
    hipMemsetAsync(Hcat, 0, D2H * sizeof(float), stream);

    pad_rows<<<dim3(1024), 256, 0, stream>>>(x, Xpad, 512, 449, 512);
    pad_rows<<<dim3(8192), 256, 0, stream>>>((const float*)d_in[1], Wpad, 2 * 2048, 449, 512);

    dim3 gz(G4 / 64, TLEN / 64, 2);
    dim3 gr(NWG, 2);

    // layer e1l0: K=512 (padded)
    gemm_btn<<<gz, 256, 0, stream>>>(Xpad, 512, Wpad, 512, (long)G4 * 512,
                                     (const float*)d_in[3], G4, Z, (long)TLEN * G4, TLEN, G4, 512);
    lstm_rec<<<gr, 256, 0, stream>>>((const float*)d_in[2], Z, bufA, flags);

    // layer e1l1
    gemm_btn<<<gz, 256, 0, stream>>>(bufA, D2H, (const float*)d_in[4], D2H, (long)G4 * D2H,
                                     (const float*)d_in[6], G4, Z, (long)TLEN * G4, TLEN, G4, D2H);
    lstm_rec<<<gr, 256, 0, stream>>>((const float*)d_in[5], Z, bufB, flags + 2 * TLEN);

    // layer e2l0
    gemm_btn<<<gz, 256, 0, stream>>>(bufB, D2H, (const float*)d_in[7], D2H, (long)G4 * D2H,
                                     (const float*)d_in[9], G4, Z, (long)TLEN * G4, TLEN, G4, D2H);
    lstm_rec<<<gr, 256, 0, stream>>>((const float*)d_in[8], Z, bufA, flags + 4 * TLEN);

    // layer e2l1 -> writes rows 1..512 of Hcat
    gemm_btn<<<gz, 256, 0, stream>>>(bufA, D2H, (const float*)d_in[10], D2H, (long)G4 * D2H,
                                     (const float*)d_in[12], G4, Z, (long)TLEN * G4, TLEN, G4, D2H);
    lstm_rec<<<gr, 256, 0, stream>>>((const float*)d_in[11], Z, Hcat + D2H, flags + 6 * TLEN);

    // heads / mods projections over Hcat [513][1024]
    gemm_btn<<<dim3(MLP / 64, 9, 1), 256, 0, stream>>>(Hcat, D2H, (const float*)d_in[13], D2H, 0,
                                                       (const float*)d_in[14], 0, heads, 0, NR, MLP, D2H);
    gemm_btn<<<dim3(MLP / 64, 9, 1), 256, 0, stream>>>(Hcat, D2H, (const float*)d_in[15], D2H, 0,
                                                       (const float*)d_in[16], 0, mods, 0, NR, MLP, D2H);

    pair_score<<<dim3(33, 33), 256, 0, stream>>>(heads, mods, (const float*)d_in[17],
                                                 (const float*)d_in[18], (float*)d_out);
}

// Round 3
// 4476.594 us; speedup vs baseline: 1.8222x; 1.8222x over previous
//
#include <hip/hip_runtime.h>
#include <math.h>

#define TLEN 512
#define G4   2048
#define HID  512
#define D2H  1024
#define MLP  256
#define NR   513
#define NWG  32

typedef unsigned long long ull;

__device__ __forceinline__ float sigm(float x) { return 1.0f / (1.0f + __expf(-x)); }
__device__ __forceinline__ float tanh_(float x) { return 1.0f - 2.0f / (1.0f + __expf(2.0f * x)); }

// ---------------- pad/copy (zero-pad K dim to multiple of 16) ----------------
__global__ __launch_bounds__(256) void pad_rows(const float* __restrict__ src,
                                                float* __restrict__ dst,
                                                int rows, int ksrc, int kdst) {
    int idx = blockIdx.x * 256 + threadIdx.x;
    if (idx >= rows * kdst) return;
    int r = idx / kdst, k = idx - r * kdst;
    dst[idx] = (k < ksrc) ? src[(long)r * ksrc + k] : 0.0f;
}

// ---------------- tiled fp32 GEMM: Out[dir][m][n] = bias[dir][n] + sum_k X[m][k]*W[dir][n][k]
__global__ __launch_bounds__(256) void gemm_btn(
    const float* __restrict__ X, int ldx,
    const float* __restrict__ W, int ldw, long wsd,
    const float* __restrict__ bias, int bsd,
    float* __restrict__ Out, long osd,
    int M, int N, int K)
{
    int dir = blockIdx.z;
    const float* Wd = W + (long)dir * wsd;
    const float* bd = bias + (long)dir * bsd;
    float* Od = Out + (long)dir * osd;
    int n0 = blockIdx.x * 64, m0 = blockIdx.y * 64;
    __shared__ float As[16][68], Bs[16][68];
    int tid = threadIdx.x;
    int ti = tid >> 4, tj = tid & 15;
    int lr = tid >> 2, lq = tid & 3;
    float acc[4][4] = {};
    for (int k0 = 0; k0 < K; k0 += 16) {
        int mrow = m0 + lr;
        float4 xa = make_float4(0.f, 0.f, 0.f, 0.f);
        if (mrow < M) xa = *(const float4*)(X + (long)mrow * ldx + k0 + lq * 4);
        As[lq * 4 + 0][lr] = xa.x; As[lq * 4 + 1][lr] = xa.y;
        As[lq * 4 + 2][lr] = xa.z; As[lq * 4 + 3][lr] = xa.w;
        float4 wa = *(const float4*)(Wd + (long)(n0 + lr) * ldw + k0 + lq * 4);
        Bs[lq * 4 + 0][lr] = wa.x; Bs[lq * 4 + 1][lr] = wa.y;
        Bs[lq * 4 + 2][lr] = wa.z; Bs[lq * 4 + 3][lr] = wa.w;
        __syncthreads();
#pragma unroll
        for (int kk = 0; kk < 16; ++kk) {
            float4 a = *(const float4*)&As[kk][ti * 4];
            float4 b = *(const float4*)&Bs[kk][tj * 4];
            acc[0][0] += a.x * b.x; acc[0][1] += a.x * b.y; acc[0][2] += a.x * b.z; acc[0][3] += a.x * b.w;
            acc[1][0] += a.y * b.x; acc[1][1] += a.y * b.y; acc[1][2] += a.y * b.z; acc[1][3] += a.y * b.w;
            acc[2][0] += a.z * b.x; acc[2][1] += a.z * b.y; acc[2][2] += a.z * b.z; acc[2][3] += a.z * b.w;
            acc[3][0] += a.w * b.x; acc[3][1] += a.w * b.y; acc[3][2] += a.w * b.z; acc[3][3] += a.w * b.w;
        }
        __syncthreads();
    }
#pragma unroll
    for (int i = 0; i < 4; ++i) {
        int m = m0 + ti * 4 + i;
        if (m < M) {
#pragma unroll
            for (int j = 0; j < 4; ++j) {
                int n = n0 + tj * 4 + j;
                Od[(long)m * N + n] = acc[i][j] + bd[n];
            }
        }
    }
}

// ---------------- persistent per-direction LSTM recurrence ----------------
// grid (NWG, 2): 32 WGs/dir, 256 threads, ONE WG per CU (launch_bounds(...,1)
// so the 128 weight floats/thread stay VGPR-resident; r2 showed VGPR=80 =>
// weights were spilling to scratch and re-read every step).
// Cross-WG handoff: each h element is a packed 64-bit (tag<<32 | h_bits)
// written with ONE relaxed agent-scope atomic store; readers poll their own
// slots until tag matches. Tag+value share one atomic object -> no fences,
// no flag hop, no same-address atomic serialization. Tags are layer-unique
// (buffer reuse safe) and never equal the 0xAA poison; Ytag is memset(0)
// at launch start so graph replays can't see stale tags.
__global__ __launch_bounds__(256, 1) void lstm_rec(
    const float* __restrict__ Whh,   // [2][2048][512]
    const float* __restrict__ Zpre,  // [2][512][2048] (= Wih@x_t + b)
    ull* __restrict__ Ytag,          // [512][1024] packed (tag,h)
    float* __restrict__ Hout,        // [512][1024] compact h for next GEMM
    unsigned tagbase)
{
    int wg = blockIdx.x;
    int dir = blockIdx.y;
    int tid = threadIdx.x;
    int rl = tid >> 2;          // local row 0..63
    int kp = tid & 3;           // k-part 0..3 (128 each)
    int g = rl >> 4;            // gate 0..3 (i,f,g,o)
    int jj = rl & 15;
    int row_global = g * 512 + wg * 16 + jj;

    const float* wrow = Whh + ((long)dir * G4 + row_global) * HID + kp * 128;
    float4 w4[32];
#pragma unroll
    for (int u = 0; u < 32; ++u) w4[u] = *(const float4*)(wrow + u * 4);

    __shared__ float hs[528];   // staged h, +4 pad per 128-block
    __shared__ float zs[64];
    float c_reg = 0.0f;

    for (int s = 0; s < TLEN; ++s) {
        int t_x = dir ? (TLEN - 1 - s) : s;
        // prefetch this step's input-projection gate values (independent of poll)
        float z_i = 0.f, z_f = 0.f, z_g = 0.f, z_o = 0.f;
        if (tid < 16) {
            const float* zp = Zpre + ((long)dir * TLEN + t_x) * G4 + wg * 16 + tid;
            z_i = zp[0]; z_f = zp[512]; z_g = zp[1024]; z_o = zp[1536];
        }
        if (s > 0) {
            int rrow = dir ? (TLEN - s) : (s - 1);
            const ull* src = Ytag + (long)rrow * D2H + dir * HID;
            unsigned expect = tagbase + (unsigned)rrow;
            int e = tid * 2;
            ull v0 = __hip_atomic_load(src + e, __ATOMIC_RELAXED, __HIP_MEMORY_SCOPE_AGENT);
            while ((unsigned)(v0 >> 32) != expect) {
                __builtin_amdgcn_s_sleep(1);
                v0 = __hip_atomic_load(src + e, __ATOMIC_RELAXED, __HIP_MEMORY_SCOPE_AGENT);
            }
            ull v1 = __hip_atomic_load(src + e + 1, __ATOMIC_RELAXED, __HIP_MEMORY_SCOPE_AGENT);
            while ((unsigned)(v1 >> 32) != expect) {
                __builtin_amdgcn_s_sleep(1);
                v1 = __hip_atomic_load(src + e + 1, __ATOMIC_RELAXED, __HIP_MEMORY_SCOPE_AGENT);
            }
            int base = e + (e >> 7) * 4;
            hs[base]     = __uint_as_float((unsigned)v0);
            hs[base + 1] = __uint_as_float((unsigned)v1);
            __syncthreads();
            const float* hp = &hs[kp * 132];
            float z = 0.0f;
#pragma unroll
            for (int u = 0; u < 32; ++u) {
                float4 hv = *(const float4*)(hp + u * 4);
                z = fmaf(w4[u].x, hv.x, z); z = fmaf(w4[u].y, hv.y, z);
                z = fmaf(w4[u].z, hv.z, z); z = fmaf(w4[u].w, hv.w, z);
            }
            z += __shfl_xor(z, 1);
            z += __shfl_xor(z, 2);
            if (kp == 0) zs[rl] = z;
            __syncthreads();
        } else {
            if (tid < 64) zs[tid] = 0.0f;
            __syncthreads();
        }
        if (tid < 16) {
            float zi = zs[tid]      + z_i;
            float zf = zs[16 + tid] + z_f;
            float zg = zs[32 + tid] + z_g;
            float zo = zs[48 + tid] + z_o;
            float ig = sigm(zi), fg = sigm(zf), gv = tanh_(zg), og = sigm(zo);
            c_reg = fg * c_reg + ig * gv;
            float h = og * tanh_(c_reg);
            int j = wg * 16 + tid;
            ull pk = ((ull)(tagbase + (unsigned)t_x) << 32) | (ull)__float_as_uint(h);
            __hip_atomic_store(Ytag + (long)t_x * D2H + dir * HID + j, pk,
                               __ATOMIC_RELAXED, __HIP_MEMORY_SCOPE_AGENT);
            Hout[(long)t_x * D2H + dir * HID + j] = h;
        }
        // no trailing barrier needed: next iter's hs writes touch a different
        // array than zs, and zs is rewritten only after the next __syncthreads.
    }
}

// ---------------- all-pairs edge scorer ----------------
__global__ __launch_bounds__(256) void pair_score(
    const float* __restrict__ heads, const float* __restrict__ mods,
    const float* __restrict__ w_s, const float* __restrict__ b_s,
    float* __restrict__ out)
{
    __shared__ float hsh[16][260], msh[16][260], wsh[256];
    int tid = threadIdx.x;
    int i0 = blockIdx.y * 16, j0 = blockIdx.x * 16;
    int r = tid >> 4, cq = tid & 15;
#pragma unroll
    for (int u = 0; u < 4; ++u) {
        int col = cq * 16 + u * 4;
        if (col < MLP) {
            float4 hv = make_float4(0.f, 0.f, 0.f, 0.f), mv = hv;
            if (i0 + r < NR) hv = *(const float4*)(heads + (long)(i0 + r) * MLP + col);
            if (j0 + r < NR) mv = *(const float4*)(mods + (long)(j0 + r) * MLP + col);
            *(float4*)&hsh[r][col] = hv;
            *(float4*)&msh[r][col] = mv;
        }
    }
    wsh[tid] = w_s[tid];
    __syncthreads();
    int ti = tid >> 4, tj = tid & 15;
    float acc = 0.0f;
#pragma unroll 4
    for (int h = 0; h < MLP; ++h) {
        acc += wsh[h] * tanh_(hsh[ti][h] + msh[tj][h]);
    }
    int i = i0 + ti, j = j0 + tj;
    if (i < NR && j < NR) out[(long)i * NR + j] = (i == j) ? 0.0f : (acc + b_s[0]);
}

extern "C" void kernel_launch(void* const* d_in, const int* in_sizes, int n_in,
                              void* d_out, int out_size, void* d_ws, size_t ws_size,
                              hipStream_t stream)
{
    const float* x = (const float*)d_in[0];
    float* ws = (float*)d_ws;
    float* Xpad  = ws;                          // 512*512
    float* Wpad  = Xpad + 512 * 512;            // 2*2048*512
    float* Z     = Wpad + 2 * 2048 * 512;       // 2*512*2048
    ull*   YtagA = (ull*)(Z + 2 * 512 * 2048);  // 512*1024 packed (4 MB)
    ull*   YtagB = YtagA + 512 * 1024;          // 512*1024 packed (4 MB)
    float* bufAc = (float*)(YtagB + 512 * 1024);// 512*1024 compact
    float* bufBc = bufAc + 512 * 1024;          // 512*1024 compact
    float* Hcat  = bufBc + 512 * 1024;          // 513*1024 (row 0 = ROOT zeros)
    float* heads = Hcat + 513 * 1024;           // 513*256
    float* mods  = heads + 513 * 256;           // 513*256

    // clear stale tags (graph replay safety) + ROOT row
    hipMemsetAsync(YtagA, 0, 2 * 512 * 1024 * sizeof(ull), stream);
    hipMemsetAsync(Hcat, 0, D2H * sizeof(float), stream);

    pad_rows<<<dim3(1024), 256, 0, stream>>>(x, Xpad, 512, 449, 512);
    pad_rows<<<dim3(8192), 256, 0, stream>>>((const float*)d_in[1], Wpad, 2 * 2048, 449, 512);

    dim3 gz(G4 / 64, TLEN / 64, 2);
    dim3 gr(NWG, 2);

    // layer e1l0: K=512 (padded)
    gemm_btn<<<gz, 256, 0, stream>>>(Xpad, 512, Wpad, 512, (long)G4 * 512,
                                     (const float*)d_in[3], G4, Z, (long)TLEN * G4, TLEN, G4, 512);
    lstm_rec<<<gr, 256, 0, stream>>>((const float*)d_in[2], Z, YtagA, bufAc, 1u * 4096u);

    // layer e1l1
    gemm_btn<<<gz, 256, 0, stream>>>(bufAc, D2H, (const float*)d_in[4], D2H, (long)G4 * D2H,
                                     (const float*)d_in[6], G4, Z, (long)TLEN * G4, TLEN, G4, D2H);
    lstm_rec<<<gr, 256, 0, stream>>>((const float*)d_in[5], Z, YtagB, bufBc, 2u * 4096u);

    // layer e2l0 (YtagA reused; layer-unique tagbase makes stale tags inert)
    gemm_btn<<<gz, 256, 0, stream>>>(bufBc, D2H, (const float*)d_in[7], D2H, (long)G4 * D2H,
                                     (const float*)d_in[9], G4, Z, (long)TLEN * G4, TLEN, G4, D2H);
    lstm_rec<<<gr, 256, 0, stream>>>((const float*)d_in[8], Z, YtagA, bufAc, 3u * 4096u);

    // layer e2l1 -> compact output goes straight into Hcat rows 1..512
    gemm_btn<<<gz, 256, 0, stream>>>(bufAc, D2H, (const float*)d_in[10], D2H, (long)G4 * D2H,
                                     (const float*)d_in[12], G4, Z, (long)TLEN * G4, TLEN, G4, D2H);
    lstm_rec<<<gr, 256, 0, stream>>>((const float*)d_in[11], Z, YtagB, Hcat + D2H, 4u * 4096u);

    // heads / mods projections over Hcat [513][1024]
    gemm_btn<<<dim3(MLP / 64, 9, 1), 256, 0, stream>>>(Hcat, D2H, (const float*)d_in[13], D2H, 0,
                                                       (const float*)d_in[14], 0, heads, 0, NR, MLP, D2H);
    gemm_btn<<<dim3(MLP / 64, 9, 1), 256, 0, stream>>>(Hcat, D2H, (const float*)d_in[15], D2H, 0,
                                                       (const float*)d_in[16], 0, mods, 0, NR, MLP, D2H);

    pair_score<<<dim3(33, 33), 256, 0, stream>>>(heads, mods, (const float*)d_in[17],
                                                 (const float*)d_in[18], (float*)d_out);
}

// Round 6
// 4436.720 us; speedup vs baseline: 1.8386x; 1.0090x over previous
//
#include <hip/hip_runtime.h>
#include <math.h>

#define TLEN 512
#define G4   2048
#define HID  512
#define D2H  1024
#define MLP  256
#define NR   513
#define NWG  32

typedef unsigned long long ull;

__device__ __forceinline__ float sigm(float x) { return 1.0f / (1.0f + __expf(-x)); }
__device__ __forceinline__ float tanh_(float x) { return 1.0f - 2.0f / (1.0f + __expf(2.0f * x)); }

// ---------------- pad/copy (zero-pad K dim to multiple of 16) ----------------
__global__ __launch_bounds__(256) void pad_rows(const float* __restrict__ src,
                                                float* __restrict__ dst,
                                                int rows, int ksrc, int kdst) {
    int idx = blockIdx.x * 256 + threadIdx.x;
    if (idx >= rows * kdst) return;
    int r = idx / kdst, k = idx - r * kdst;
    dst[idx] = (k < ksrc) ? src[(long)r * ksrc + k] : 0.0f;
}

// ---------------- tiled fp32 GEMM: Out[dir][m][n] = bias[dir][n] + sum_k X[m][k]*W[dir][n][k]
__global__ __launch_bounds__(256) void gemm_btn(
    const float* __restrict__ X, int ldx,
    const float* __restrict__ W, int ldw, long wsd,
    const float* __restrict__ bias, int bsd,
    float* __restrict__ Out, long osd,
    int M, int N, int K)
{
    int dir = blockIdx.z;
    const float* Wd = W + (long)dir * wsd;
    const float* bd = bias + (long)dir * bsd;
    float* Od = Out + (long)dir * osd;
    int n0 = blockIdx.x * 64, m0 = blockIdx.y * 64;
    __shared__ float As[16][68], Bs[16][68];
    int tid = threadIdx.x;
    int ti = tid >> 4, tj = tid & 15;
    int lr = tid >> 2, lq = tid & 3;
    float acc[4][4] = {};
    for (int k0 = 0; k0 < K; k0 += 16) {
        int mrow = m0 + lr;
        float4 xa = make_float4(0.f, 0.f, 0.f, 0.f);
        if (mrow < M) xa = *(const float4*)(X + (long)mrow * ldx + k0 + lq * 4);
        As[lq * 4 + 0][lr] = xa.x; As[lq * 4 + 1][lr] = xa.y;
        As[lq * 4 + 2][lr] = xa.z; As[lq * 4 + 3][lr] = xa.w;
        float4 wa = *(const float4*)(Wd + (long)(n0 + lr) * ldw + k0 + lq * 4);
        Bs[lq * 4 + 0][lr] = wa.x; Bs[lq * 4 + 1][lr] = wa.y;
        Bs[lq * 4 + 2][lr] = wa.z; Bs[lq * 4 + 3][lr] = wa.w;
        __syncthreads();
#pragma unroll
        for (int kk = 0; kk < 16; ++kk) {
            float4 a = *(const float4*)&As[kk][ti * 4];
            float4 b = *(const float4*)&Bs[kk][tj * 4];
            acc[0][0] += a.x * b.x; acc[0][1] += a.x * b.y; acc[0][2] += a.x * b.z; acc[0][3] += a.x * b.w;
            acc[1][0] += a.y * b.x; acc[1][1] += a.y * b.y; acc[1][2] += a.y * b.z; acc[1][3] += a.y * b.w;
            acc[2][0] += a.z * b.x; acc[2][1] += a.z * b.y; acc[2][2] += a.z * b.z; acc[2][3] += a.z * b.w;
            acc[3][0] += a.w * b.x; acc[3][1] += a.w * b.y; acc[3][2] += a.w * b.z; acc[3][3] += a.w * b.w;
        }
        __syncthreads();
    }
#pragma unroll
    for (int i = 0; i < 4; ++i) {
        int m = m0 + ti * 4 + i;
        if (m < M) {
#pragma unroll
            for (int j = 0; j < 4; ++j) {
                int n = n0 + tj * 4 + j;
                Od[(long)m * N + n] = acc[i][j] + bd[n];
            }
        }
    }
}

// ---------------- persistent per-direction LSTM recurrence ----------------
// grid (NWG, 2): 32 WGs/dir, 256 threads, 1 WG/CU.
// Thread layout: c = tid&15 (32-col slice), rgrp = tid>>4 (4 consecutive gate
// rows). Weights = 32 NAMED float4 (no array -> cannot be demoted to scratch;
// r3 showed VGPR=84, i.e. the float4 w4[32] array never SROA'd and was
// re-read from scratch every step). 4 independent accumulators break the
// serial fmaf chain. h broadcast via LDS stage (8 ds_read_b128/thread).
// Cross-WG handoff: packed 64-bit (tag<<32 | h_bits) relaxed agent atomics;
// readers poll their own slots; tags layer-unique; Ytag memset each launch.
#define LDR(P, ptr) \
    P##0 = ((const float4*)(ptr))[0]; P##1 = ((const float4*)(ptr))[1]; \
    P##2 = ((const float4*)(ptr))[2]; P##3 = ((const float4*)(ptr))[3]; \
    P##4 = ((const float4*)(ptr))[4]; P##5 = ((const float4*)(ptr))[5]; \
    P##6 = ((const float4*)(ptr))[6]; P##7 = ((const float4*)(ptr))[7];

#define DOT4(I) { float4 hv = *(const float4*)(hp + 4 * I); \
    z0 = fmaf(wA##I.x, hv.x, z0); z0 = fmaf(wA##I.y, hv.y, z0); \
    z0 = fmaf(wA##I.z, hv.z, z0); z0 = fmaf(wA##I.w, hv.w, z0); \
    z1 = fmaf(wB##I.x, hv.x, z1); z1 = fmaf(wB##I.y, hv.y, z1); \
    z1 = fmaf(wB##I.z, hv.z, z1); z1 = fmaf(wB##I.w, hv.w, z1); \
    z2 = fmaf(wC##I.x, hv.x, z2); z2 = fmaf(wC##I.y, hv.y, z2); \
    z2 = fmaf(wC##I.z, hv.z, z2); z2 = fmaf(wC##I.w, hv.w, z2); \
    z3 = fmaf(wD##I.x, hv.x, z3); z3 = fmaf(wD##I.y, hv.y, z3); \
    z3 = fmaf(wD##I.z, hv.z, z3); z3 = fmaf(wD##I.w, hv.w, z3); }

__global__ __launch_bounds__(256, 1) void lstm_rec(
    const float* __restrict__ Whh,   // [2][2048][512]
    const float* __restrict__ Zpre,  // [2][512][2048] (= Wih@x_t + b)
    ull* __restrict__ Ytag,          // [512][1024] packed (tag,h)
    float* __restrict__ Hout,        // [512][1024] compact h for next GEMM
    unsigned tagbase)
{
    int wg = blockIdx.x;
    int dir = blockIdx.y;
    int tid = threadIdx.x;
    int c = tid & 15;           // col-slice: cols c*32 .. c*32+31
    int rgrp = tid >> 4;        // row group: local rows rgrp*4 .. rgrp*4+3

    // local row lr = g*16 + jj ; lr = rgrp*4+r  =>  g = rgrp>>2, jj = (rgrp&3)*4+r
    const float* pA = Whh + ((long)dir * G4 + (rgrp >> 2) * 512 + wg * 16 + (rgrp & 3) * 4) * HID + c * 32;
    float4 wA0, wA1, wA2, wA3, wA4, wA5, wA6, wA7;
    float4 wB0, wB1, wB2, wB3, wB4, wB5, wB6, wB7;
    float4 wC0, wC1, wC2, wC3, wC4, wC5, wC6, wC7;
    float4 wD0, wD1, wD2, wD3, wD4, wD5, wD6, wD7;
    LDR(wA, pA)
    LDR(wB, pA + HID)
    LDR(wC, pA + 2 * HID)
    LDR(wD, pA + 3 * HID)

    __shared__ float hs[576];   // 512 staged h + 4-float pad per 32-block
    __shared__ float zs[64];
    float c_reg = 0.0f;

    for (int s = 0; s < TLEN; ++s) {
        int t_x = dir ? (TLEN - 1 - s) : s;
        // prefetch this step's input-projection gate values (independent of poll)
        float z_i = 0.f, z_f = 0.f, z_g = 0.f, z_o = 0.f;
        if (tid < 16) {
            const float* zp = Zpre + ((long)dir * TLEN + t_x) * G4 + wg * 16 + tid;
            z_i = zp[0]; z_f = zp[512]; z_g = zp[1024]; z_o = zp[1536];
        }
        if (s > 0) {
            int rrow = dir ? (TLEN - s) : (s - 1);
            const ull* src = Ytag + (long)rrow * D2H + dir * HID;
            unsigned expect = tagbase + (unsigned)rrow;
            int e = tid * 2;
            // issue both loads, then poll each (overlaps the two round trips)
            ull v0 = __hip_atomic_load(src + e,     __ATOMIC_RELAXED, __HIP_MEMORY_SCOPE_AGENT);
            ull v1 = __hip_atomic_load(src + e + 1, __ATOMIC_RELAXED, __HIP_MEMORY_SCOPE_AGENT);
            while ((unsigned)(v0 >> 32) != expect) {
                __builtin_amdgcn_s_sleep(1);
                v0 = __hip_atomic_load(src + e, __ATOMIC_RELAXED, __HIP_MEMORY_SCOPE_AGENT);
            }
            while ((unsigned)(v1 >> 32) != expect) {
                __builtin_amdgcn_s_sleep(1);
                v1 = __hip_atomic_load(src + e + 1, __ATOMIC_RELAXED, __HIP_MEMORY_SCOPE_AGENT);
            }
            int base = e + ((e >> 5) << 2);
            hs[base]     = __uint_as_float((unsigned)v0);
            hs[base + 1] = __uint_as_float((unsigned)v1);
            __syncthreads();
            const float* hp = &hs[c * 36];
            float z0 = 0.f, z1 = 0.f, z2 = 0.f, z3 = 0.f;
            DOT4(0) DOT4(1) DOT4(2) DOT4(3) DOT4(4) DOT4(5) DOT4(6) DOT4(7)
            // butterfly over the 16 col-slices (lanes c, within wave)
            z0 += __shfl_xor(z0, 1); z0 += __shfl_xor(z0, 2); z0 += __shfl_xor(z0, 4); z0 += __shfl_xor(z0, 8);
            z1 += __shfl_xor(z1, 1); z1 += __shfl_xor(z1, 2); z1 += __shfl_xor(z1, 4); z1 += __shfl_xor(z1, 8);
            z2 += __shfl_xor(z2, 1); z2 += __shfl_xor(z2, 2); z2 += __shfl_xor(z2, 4); z2 += __shfl_xor(z2, 8);
            z3 += __shfl_xor(z3, 1); z3 += __shfl_xor(z3, 2); z3 += __shfl_xor(z3, 4); z3 += __shfl_xor(z3, 8);
            if (c < 4) {
                float zv = (c == 0) ? z0 : (c == 1) ? z1 : (c == 2) ? z2 : z3;
                zs[rgrp * 4 + c] = zv;
            }
            __syncthreads();
        } else {
            if (tid < 64) zs[tid] = 0.0f;
            __syncthreads();
        }
        if (tid < 16) {
            float zi = zs[tid]      + z_i;
            float zf = zs[16 + tid] + z_f;
            float zg = zs[32 + tid] + z_g;
            float zo = zs[48 + tid] + z_o;
            float ig = sigm(zi), fg = sigm(zf), gv = tanh_(zg), og = sigm(zo);
            c_reg = fg * c_reg + ig * gv;
            float h = og * tanh_(c_reg);
            int j = wg * 16 + tid;
            ull pk = ((ull)(tagbase + (unsigned)t_x) << 32) | (ull)__float_as_uint(h);
            __hip_atomic_store(Ytag + (long)t_x * D2H + dir * HID + j, pk,
                               __ATOMIC_RELAXED, __HIP_MEMORY_SCOPE_AGENT);
            Hout[(long)t_x * D2H + dir * HID + j] = h;
        }
        // no trailing barrier needed: hs (next iter) is written only after the
        // post-dot __syncthreads above; zs is rewritten only after the next one.
    }
}

// ---------------- all-pairs edge scorer ----------------
__global__ __launch_bounds__(256) void pair_score(
    const float* __restrict__ heads, const float* __restrict__ mods,
    const float* __restrict__ w_s, const float* __restrict__ b_s,
    float* __restrict__ out)
{
    __shared__ float hsh[16][260], msh[16][260], wsh[256];
    int tid = threadIdx.x;
    int i0 = blockIdx.y * 16, j0 = blockIdx.x * 16;
    int r = tid >> 4, cq = tid & 15;
#pragma unroll
    for (int u = 0; u < 4; ++u) {
        int col = cq * 16 + u * 4;
        if (col < MLP) {
            float4 hv = make_float4(0.f, 0.f, 0.f, 0.f), mv = hv;
            if (i0 + r < NR) hv = *(const float4*)(heads + (long)(i0 + r) * MLP + col);
            if (j0 + r < NR) mv = *(const float4*)(mods + (long)(j0 + r) * MLP + col);
            *(float4*)&hsh[r][col] = hv;
            *(float4*)&msh[r][col] = mv;
        }
    }
    wsh[tid] = w_s[tid];
    __syncthreads();
    int ti = tid >> 4, tj = tid & 15;
    float acc = 0.0f;
#pragma unroll 4
    for (int h = 0; h < MLP; ++h) {
        acc += wsh[h] * tanh_(hsh[ti][h] + msh[tj][h]);
    }
    int i = i0 + ti, j = j0 + tj;
    if (i < NR && j < NR) out[(long)i * NR + j] = (i == j) ? 0.0f : (acc + b_s[0]);
}

extern "C" void kernel_launch(void* const* d_in, const int* in_sizes, int n_in,
                              void* d_out, int out_size, void* d_ws, size_t ws_size,
                              hipStream_t stream)
{
    const float* x = (const float*)d_in[0];
    float* ws = (float*)d_ws;
    float* Xpad  = ws;                          // 512*512
    float* Wpad  = Xpad + 512 * 512;            // 2*2048*512
    float* Z     = Wpad + 2 * 2048 * 512;       // 2*512*2048
    ull*   YtagA = (ull*)(Z + 2 * 512 * 2048);  // 512*1024 packed (4 MB)
    ull*   YtagB = YtagA + 512 * 1024;          // 512*1024 packed (4 MB)
    float* bufAc = (float*)(YtagB + 512 * 1024);// 512*1024 compact
    float* bufBc = bufAc + 512 * 1024;          // 512*1024 compact
    float* Hcat  = bufBc + 512 * 1024;          // 513*1024 (row 0 = ROOT zeros)
    float* heads = Hcat + 513 * 1024;           // 513*256
    float* mods  = heads + 513 * 256;           // 513*256

    // clear stale tags (graph replay safety) + ROOT row
    hipMemsetAsync(YtagA, 0, 2 * 512 * 1024 * sizeof(ull), stream);
    hipMemsetAsync(Hcat, 0, D2H * sizeof(float), stream);

    pad_rows<<<dim3(1024), 256, 0, stream>>>(x, Xpad, 512, 449, 512);
    pad_rows<<<dim3(8192), 256, 0, stream>>>((const float*)d_in[1], Wpad, 2 * 2048, 449, 512);

    dim3 gz(G4 / 64, TLEN / 64, 2);
    dim3 gr(NWG, 2);

    // layer e1l0: K=512 (padded)
    gemm_btn<<<gz, 256, 0, stream>>>(Xpad, 512, Wpad, 512, (long)G4 * 512,
                                     (const float*)d_in[3], G4, Z, (long)TLEN * G4, TLEN, G4, 512);
    lstm_rec<<<gr, 256, 0, stream>>>((const float*)d_in[2], Z, YtagA, bufAc, 1u * 4096u);

    // layer e1l1
    gemm_btn<<<gz, 256, 0, stream>>>(bufAc, D2H, (const float*)d_in[4], D2H, (long)G4 * D2H,
                                     (const float*)d_in[6], G4, Z, (long)TLEN * G4, TLEN, G4, D2H);
    lstm_rec<<<gr, 256, 0, stream>>>((const float*)d_in[5], Z, YtagB, bufBc, 2u * 4096u);

    // layer e2l0 (YtagA reused; layer-unique tagbase makes stale tags inert)
    gemm_btn<<<gz, 256, 0, stream>>>(bufBc, D2H, (const float*)d_in[7], D2H, (long)G4 * D2H,
                                     (const float*)d_in[9], G4, Z, (long)TLEN * G4, TLEN, G4, D2H);
    lstm_rec<<<gr, 256, 0, stream>>>((const float*)d_in[8], Z, YtagA, bufAc, 3u * 4096u);

    // layer e2l1 -> compact output goes straight into Hcat rows 1..512
    gemm_btn<<<gz, 256, 0, stream>>>(bufAc, D2H, (const float*)d_in[10], D2H, (long)G4 * D2H,
                                     (const float*)d_in[12], G4, Z, (long)TLEN * G4, TLEN, G4, D2H);
    lstm_rec<<<gr, 256, 0, stream>>>((const float*)d_in[11], Z, YtagB, Hcat + D2H, 4u * 4096u);

    // heads / mods projections over Hcat [513][1024]
    gemm_btn<<<dim3(MLP / 64, 9, 1), 256, 0, stream>>>(Hcat, D2H, (const float*)d_in[13], D2H, 0,
                                                       (const float*)d_in[14], 0, heads, 0, NR, MLP, D2H);
    gemm_btn<<<dim3(MLP / 64, 9, 1), 256, 0, stream>>>(Hcat, D2H, (const float*)d_in[15], D2H, 0,
                                                       (const float*)d_in[16], 0, mods, 0, NR, MLP, D2H);

    pair_score<<<dim3(33, 33), 256, 0, stream>>>(heads, mods, (const float*)d_in[17],
                                                 (const float*)d_in[18], (float*)d_out);
}